// Round 3
// baseline (132.009 us; speedup 1.0000x reference)
//
#include <hip/hip_runtime.h>
#include <math.h>

namespace {

constexpr int NB = 8;     // batch
constexpr int NS = 48;    // samples
constexpr int NA = 8192;  // atoms
constexpr int BSIZE = 256;
constexpr int CH = 4;     // chunks per (b,s), 2048 atoms each
constexpr int NBS = NB * NS;    // 384
constexpr int GRID = CH * NBS;  // 1536

// ws layout (floats):
// [0 .. NBS*CH*16)      per-(b,s,chunk) partials, 13 used of 16: idx (bs*CH+c)*16
// [PBOFF .. +NB*CH*8)   per-(b,chunk) stats, 6 used of 8: idx (b*CH+c)*8
// [CNTOFF]              uint32 completion counter (memset to 0 each launch)
constexpr int PBOFF = NBS * CH * 16;        // 24576
constexpr int CNTOFF = PBOFF + NB * CH * 8; // 24832

template <int CNT>
__device__ inline void blockReduceWrite(const float (&v)[CNT], float* __restrict__ dst,
                                        float* lds) {
  const int lane = threadIdx.x & 63;
  const int wave = threadIdx.x >> 6;
#pragma unroll
  for (int k = 0; k < CNT; ++k) {
    float x = v[k];
#pragma unroll
    for (int off = 32; off; off >>= 1) x += __shfl_xor(x, off, 64);
    if (lane == 0) lds[wave * CNT + k] = x;
  }
  __syncthreads();
  if ((int)threadIdx.x < CNT) {
    float s = 0.f;
#pragma unroll
    for (int w = 0; w < BSIZE / 64; ++w) s += lds[w * CNT + threadIdx.x];
    dst[threadIdx.x] = s;
  }
  __syncthreads();
}

__device__ void finalize(const float* __restrict__ ws, const float* __restrict__ scale,
                         float* __restrict__ out) {
  const int tid = threadIdx.x;
  __shared__ double bv[NB][6];

  if (tid < NB) {
    double s[6] = {0, 0, 0, 0, 0, 0};
    for (int c = 0; c < CH; ++c) {
      const float* q = ws + PBOFF + (tid * CH + c) * 8;
#pragma unroll
      for (int k = 0; k < 6; ++k) s[k] += (double)q[k];
    }
#pragma unroll
    for (int k = 0; k < 6; ++k) bv[tid][k] = s[k];
  }
  __syncthreads();

  double tot = 0.0;
  for (int bs = tid; bs < NBS; bs += BSIZE) {
    const int b = bs / NS;
    double sums[13];
#pragma unroll
    for (int k = 0; k < 13; ++k) sums[k] = 0.0;
    for (int c = 0; c < CH; ++c) {
      const float* q = ws + (size_t)(bs * CH + c) * 16;
#pragma unroll
      for (int k = 0; k < 13; ++k) sums[k] += (double)q[k];
    }

    const double wsum = bv[b][0];
    const double St[3] = {bv[b][1], bv[b][2], bv[b][3]};
    const double stt = bv[b][4];
    const double msum = bv[b][5];

    const double spp = sums[0];
    const double Sp[3] = {sums[1], sums[2], sums[3]};
    const double inv = 1.0 / wsum;

    double H[3][3];
#pragma unroll
    for (int i = 0; i < 3; ++i)
#pragma unroll
      for (int j = 0; j < 3; ++j) H[i][j] = sums[4 + 3 * i + j] - Sp[i] * St[j] * inv;

    const double Sq = spp - (Sp[0] * Sp[0] + Sp[1] * Sp[1] + Sp[2] * Sp[2]) * inv;
    const double Sy = stt - (St[0] * St[0] + St[1] * St[1] + St[2] * St[2]) * inv;

    double K[3][3];
#pragma unroll
    for (int i = 0; i < 3; ++i)
#pragma unroll
      for (int j = 0; j < 3; ++j)
        K[i][j] = H[0][i] * H[0][j] + H[1][i] * H[1][j] + H[2][i] * H[2][j];

    const double q = (K[0][0] + K[1][1] + K[2][2]) / 3.0;
    const double p1 = K[0][1] * K[0][1] + K[0][2] * K[0][2] + K[1][2] * K[1][2];
    const double a0 = K[0][0] - q, a1 = K[1][1] - q, a2 = K[2][2] - q;
    const double p2 = a0 * a0 + a1 * a1 + a2 * a2 + 2.0 * p1;
    double e1, e2, e3;
    if (p2 <= 1e-300) {
      e1 = e2 = e3 = q;
    } else {
      const double pp = sqrt(p2 / 6.0);
      const double ip = 1.0 / pp;
      const double B00 = a0 * ip, B11 = a1 * ip, B22 = a2 * ip;
      const double B01 = K[0][1] * ip, B02 = K[0][2] * ip, B12 = K[1][2] * ip;
      double r = 0.5 * (B00 * (B11 * B22 - B12 * B12) - B01 * (B01 * B22 - B12 * B02) +
                        B02 * (B01 * B12 - B11 * B02));
      float rf = fminf(1.0f, fmaxf(-1.0f, (float)r));
      const float phi = acosf(rf) * (1.0f / 3.0f);
      e1 = q + 2.0 * pp * (double)cosf(phi);
      e3 = q + 2.0 * pp * (double)cosf(phi + 2.0943951023931953f);
      e2 = 3.0 * q - e1 - e3;
    }
    const double s1 = sqrt(fmax(e1, 0.0));
    const double s2 = sqrt(fmax(e2, 0.0));
    const double s3 = sqrt(fmax(e3, 0.0));

    const double detH =
        H[0][0] * (H[1][1] * H[2][2] - H[1][2] * H[2][1]) -
        H[0][1] * (H[1][0] * H[2][2] - H[1][2] * H[2][0]) +
        H[0][2] * (H[1][0] * H[2][1] - H[1][1] * H[2][0]);
    const double d = (detH > 0.0) ? 1.0 : ((detH < 0.0) ? -1.0 : 0.0);

    const double cost = Sq + Sy - 2.0 * (s1 + s2 + d * s3);
    tot += cost / (msum + 1e-6) * (double)scale[bs];
  }

#pragma unroll
  for (int off = 32; off; off >>= 1) tot += __shfl_xor(tot, off, 64);
  __shared__ double red[BSIZE / 64];
  if ((tid & 63) == 0) red[tid >> 6] = tot;
  __syncthreads();
  if (tid == 0) {
    double s = 0.0;
#pragma unroll
    for (int w = 0; w < BSIZE / 64; ++w) s += red[w];
    out[0] = (float)(s * (1.0 / (3.0 * (double)NS * (double)NB)));
  }
}

__global__ __launch_bounds__(BSIZE) void fused_kernel(
    const float* __restrict__ pred, const float* __restrict__ truec,
    const int* __restrict__ mask, const int* __restrict__ dna,
    const int* __restrict__ rna, const int* __restrict__ lig,
    const float* __restrict__ scale, float* __restrict__ ws,
    float* __restrict__ out) {
  __shared__ float lds[(BSIZE / 64) * 13];
  const int blk = blockIdx.x;
  const int c = blk / NBS;   // chunk-major: concurrent blocks share true/mask slices
  const int bs = blk % NBS;
  const int b = bs / NS;
  const bool isS0 = (bs % NS) == 0;

  const float* p = pred + (size_t)bs * NA * 3;
  const float* t = truec + (size_t)b * NA * 3;
  const int mbase = b * NA;

  float acc[13];
#pragma unroll
  for (int k = 0; k < 13; ++k) acc[k] = 0.f;
  float accb[6];
#pragma unroll
  for (int k = 0; k < 6; ++k) accb[k] = 0.f;

  auto atom = [&](float w, float p0, float p1, float p2, float t0, float t1, float t2) {
    const float wp0 = w * p0, wp1 = w * p1, wp2 = w * p2;
    acc[0] += wp0 * p0 + wp1 * p1 + wp2 * p2;
    acc[1] += wp0;
    acc[2] += wp1;
    acc[3] += wp2;
    acc[4] += wp0 * t0;
    acc[5] += wp0 * t1;
    acc[6] += wp0 * t2;
    acc[7] += wp1 * t0;
    acc[8] += wp1 * t1;
    acc[9] += wp1 * t2;
    acc[10] += wp2 * t0;
    acc[11] += wp2 * t1;
    acc[12] += wp2 * t2;
  };
  auto atomb = [&](float mf, float w, float t0, float t1, float t2) {
    accb[0] += w;
    accb[1] += w * t0;
    accb[2] += w * t1;
    accb[3] += w * t2;
    accb[4] += w * (t0 * t0 + t1 * t1 + t2 * t2);
    accb[5] += mf;
  };
  auto wgt = [](int m, int d, int r, int l) {
    return (float)((1 + 5 * (d + r) + 10 * l) * m);
  };

#pragma unroll
  for (int it = 0; it < 2; ++it) {
    const int n0 = c * 2048 + it * 1024 + threadIdx.x * 4;
    const float4 pa = *(const float4*)(p + 3 * n0);
    const float4 pb = *(const float4*)(p + 3 * n0 + 4);
    const float4 pc = *(const float4*)(p + 3 * n0 + 8);
    const float4 ta = *(const float4*)(t + 3 * n0);
    const float4 tb = *(const float4*)(t + 3 * n0 + 4);
    const float4 tc = *(const float4*)(t + 3 * n0 + 8);
    const int4 mk = *(const int4*)(mask + mbase + n0);
    const int4 dn = *(const int4*)(dna + mbase + n0);
    const int4 rn = *(const int4*)(rna + mbase + n0);
    const int4 lg = *(const int4*)(lig + mbase + n0);

    const float w0 = wgt(mk.x, dn.x, rn.x, lg.x);
    const float w1 = wgt(mk.y, dn.y, rn.y, lg.y);
    const float w2 = wgt(mk.z, dn.z, rn.z, lg.z);
    const float w3 = wgt(mk.w, dn.w, rn.w, lg.w);

    atom(w0, pa.x, pa.y, pa.z, ta.x, ta.y, ta.z);
    atom(w1, pa.w, pb.x, pb.y, ta.w, tb.x, tb.y);
    atom(w2, pb.z, pb.w, pc.x, tb.z, tb.w, tc.x);
    atom(w3, pc.y, pc.z, pc.w, tc.y, tc.z, tc.w);

    if (isS0) {  // block-uniform branch: only 32/1536 blocks
      atomb((float)mk.x, w0, ta.x, ta.y, ta.z);
      atomb((float)mk.y, w1, ta.w, tb.x, tb.y);
      atomb((float)mk.z, w2, tb.z, tb.w, tc.x);
      atomb((float)mk.w, w3, tc.y, tc.z, tc.w);
    }
  }

  blockReduceWrite<13>(acc, ws + (size_t)(bs * CH + c) * 16, lds);
  if (isS0) blockReduceWrite<6>(accb, ws + PBOFF + (size_t)(b * CH + c) * 8, lds);

  // --- last-block finalize ---
  __threadfence();  // agent-scope release: partials visible device-wide
  __shared__ unsigned amLast;
  if (threadIdx.x == 0) {
    unsigned old = atomicAdd((unsigned*)(ws + CNTOFF), 1u);
    amLast = (old == (unsigned)(GRID - 1)) ? 1u : 0u;
  }
  __syncthreads();
  if (amLast) {
    __threadfence();  // agent-scope acquire: invalidate stale cache lines
    finalize(ws, scale, out);
  }
}

}  // namespace

extern "C" void kernel_launch(void* const* d_in, const int* in_sizes, int n_in,
                              void* d_out, int out_size, void* d_ws, size_t ws_size,
                              hipStream_t stream) {
  const float* pred = (const float*)d_in[0];
  const float* truec = (const float*)d_in[1];
  const int* mask = (const int*)d_in[2];
  const int* dna = (const int*)d_in[3];
  const int* rna = (const int*)d_in[4];
  const int* lig = (const int*)d_in[5];
  const float* scale = (const float*)d_in[6];
  float* ws = (float*)d_ws;
  float* out = (float*)d_out;

  hipMemsetAsync((char*)d_ws + (size_t)CNTOFF * 4, 0, 4, stream);
  fused_kernel<<<GRID, BSIZE, 0, stream>>>(pred, truec, mask, dna, rna, lig, scale, ws, out);
}

// Round 4
// 25.044 us; speedup vs baseline: 5.2711x; 5.2711x over previous
//
#include <hip/hip_runtime.h>
#include <math.h>

namespace {

constexpr int NB = 8;     // batch
constexpr int NS = 48;    // samples
constexpr int NA = 8192;  // atoms
constexpr int BSIZE = 256;
constexpr int CH = 4;     // chunks per (b,s), 2048 atoms each
constexpr int NBS = NB * NS;    // 384
constexpr int GRID = CH * NBS;  // 1536
constexpr int FBS = NBS;        // final kernel block size (384)

// ws layout (floats):
// [0 .. NBS*CH*16)      per-(b,s,chunk) partials, 13 used of 16: idx (bs*CH+c)*16
// [PBOFF .. +NB*CH*8)   per-(b,chunk) stats, 6 used of 8: idx (b*CH+c)*8
constexpr int PBOFF = NBS * CH * 16;  // 24576

template <int CNT>
__device__ inline void blockReduceWrite(const float (&v)[CNT], float* __restrict__ dst,
                                        float* lds) {
  const int lane = threadIdx.x & 63;
  const int wave = threadIdx.x >> 6;
#pragma unroll
  for (int k = 0; k < CNT; ++k) {
    float x = v[k];
#pragma unroll
    for (int off = 32; off; off >>= 1) x += __shfl_xor(x, off, 64);
    if (lane == 0) lds[wave * CNT + k] = x;
  }
  __syncthreads();
  if ((int)threadIdx.x < CNT) {
    float s = 0.f;
#pragma unroll
    for (int w = 0; w < BSIZE / 64; ++w) s += lds[w * CNT + threadIdx.x];
    dst[threadIdx.x] = s;
  }
  __syncthreads();
}

__global__ __launch_bounds__(BSIZE) void fused_kernel(
    const float* __restrict__ pred, const float* __restrict__ truec,
    const int* __restrict__ mask, const int* __restrict__ dna,
    const int* __restrict__ rna, const int* __restrict__ lig,
    float* __restrict__ ws) {
  __shared__ float lds[(BSIZE / 64) * 13];
  const int blk = blockIdx.x;
  const int c = blk / NBS;
  const int bs = blk % NBS;
  const int b = bs / NS;
  const bool isS0 = (bs % NS) == 0;

  const float* p = pred + (size_t)bs * NA * 3;
  const float* t = truec + (size_t)b * NA * 3;
  const int mbase = b * NA;

  float acc[13];
#pragma unroll
  for (int k = 0; k < 13; ++k) acc[k] = 0.f;
  float accb[6];
#pragma unroll
  for (int k = 0; k < 6; ++k) accb[k] = 0.f;

  auto atom = [&](float w, float p0, float p1, float p2, float t0, float t1, float t2) {
    const float wp0 = w * p0, wp1 = w * p1, wp2 = w * p2;
    acc[0] += wp0 * p0 + wp1 * p1 + wp2 * p2;
    acc[1] += wp0;
    acc[2] += wp1;
    acc[3] += wp2;
    acc[4] += wp0 * t0;
    acc[5] += wp0 * t1;
    acc[6] += wp0 * t2;
    acc[7] += wp1 * t0;
    acc[8] += wp1 * t1;
    acc[9] += wp1 * t2;
    acc[10] += wp2 * t0;
    acc[11] += wp2 * t1;
    acc[12] += wp2 * t2;
  };
  auto atomb = [&](float mf, float w, float t0, float t1, float t2) {
    accb[0] += w;
    accb[1] += w * t0;
    accb[2] += w * t1;
    accb[3] += w * t2;
    accb[4] += w * (t0 * t0 + t1 * t1 + t2 * t2);
    accb[5] += mf;
  };
  auto wgt = [](int m, int d, int r, int l) {
    return (float)((1 + 5 * (d + r) + 10 * l) * m);
  };

#pragma unroll
  for (int it = 0; it < 2; ++it) {
    const int n0 = c * 2048 + it * 1024 + threadIdx.x * 4;
    const float4 pa = *(const float4*)(p + 3 * n0);
    const float4 pb = *(const float4*)(p + 3 * n0 + 4);
    const float4 pc = *(const float4*)(p + 3 * n0 + 8);
    const float4 ta = *(const float4*)(t + 3 * n0);
    const float4 tb = *(const float4*)(t + 3 * n0 + 4);
    const float4 tc = *(const float4*)(t + 3 * n0 + 8);
    const int4 mk = *(const int4*)(mask + mbase + n0);
    const int4 dn = *(const int4*)(dna + mbase + n0);
    const int4 rn = *(const int4*)(rna + mbase + n0);
    const int4 lg = *(const int4*)(lig + mbase + n0);

    const float w0 = wgt(mk.x, dn.x, rn.x, lg.x);
    const float w1 = wgt(mk.y, dn.y, rn.y, lg.y);
    const float w2 = wgt(mk.z, dn.z, rn.z, lg.z);
    const float w3 = wgt(mk.w, dn.w, rn.w, lg.w);

    atom(w0, pa.x, pa.y, pa.z, ta.x, ta.y, ta.z);
    atom(w1, pa.w, pb.x, pb.y, ta.w, tb.x, tb.y);
    atom(w2, pb.z, pb.w, pc.x, tb.z, tb.w, tc.x);
    atom(w3, pc.y, pc.z, pc.w, tc.y, tc.z, tc.w);

    if (isS0) {  // block-uniform branch: only 32/1536 blocks
      atomb((float)mk.x, w0, ta.x, ta.y, ta.z);
      atomb((float)mk.y, w1, ta.w, tb.x, tb.y);
      atomb((float)mk.z, w2, tb.z, tb.w, tc.x);
      atomb((float)mk.w, w3, tc.y, tc.z, tc.w);
    }
  }

  blockReduceWrite<13>(acc, ws + (size_t)(bs * CH + c) * 16, lds);
  if (isS0) blockReduceWrite<6>(accb, ws + PBOFF + (size_t)(b * CH + c) * 8, lds);
}

__global__ __launch_bounds__(FBS) void final_kernel(const float* __restrict__ ws,
                                                    const float* __restrict__ scale,
                                                    float* __restrict__ out) {
  const int tid = threadIdx.x;  // 0..383, tid = bs = b*NS + s
  __shared__ double bv[NB][6];

  if (tid < NB) {
    double s[6] = {0, 0, 0, 0, 0, 0};
    for (int c = 0; c < CH; ++c) {
      const float* q = ws + PBOFF + (tid * CH + c) * 8;
#pragma unroll
      for (int k = 0; k < 6; ++k) s[k] += (double)q[k];
    }
#pragma unroll
    for (int k = 0; k < 6; ++k) bv[tid][k] = s[k];
  }
  __syncthreads();

  const int b = tid / NS;
  double sums[13];
#pragma unroll
  for (int k = 0; k < 13; ++k) sums[k] = 0.0;
  for (int c = 0; c < CH; ++c) {
    const float4* q4 = (const float4*)(ws + (size_t)(tid * CH + c) * 16);
    const float4 qa = q4[0], qb = q4[1], qc = q4[2], qd = q4[3];
    sums[0] += (double)qa.x;  sums[1] += (double)qa.y;
    sums[2] += (double)qa.z;  sums[3] += (double)qa.w;
    sums[4] += (double)qb.x;  sums[5] += (double)qb.y;
    sums[6] += (double)qb.z;  sums[7] += (double)qb.w;
    sums[8] += (double)qc.x;  sums[9] += (double)qc.y;
    sums[10] += (double)qc.z; sums[11] += (double)qc.w;
    sums[12] += (double)qd.x;
  }

  const double wsum = bv[b][0];
  const double St[3] = {bv[b][1], bv[b][2], bv[b][3]};
  const double stt = bv[b][4];
  const double msum = bv[b][5];

  const double spp = sums[0];
  const double Sp[3] = {sums[1], sums[2], sums[3]};
  const double inv = 1.0 / wsum;

  double H[3][3];
#pragma unroll
  for (int i = 0; i < 3; ++i)
#pragma unroll
    for (int j = 0; j < 3; ++j) H[i][j] = sums[4 + 3 * i + j] - Sp[i] * St[j] * inv;

  const double Sq = spp - (Sp[0] * Sp[0] + Sp[1] * Sp[1] + Sp[2] * Sp[2]) * inv;
  const double Sy = stt - (St[0] * St[0] + St[1] * St[1] + St[2] * St[2]) * inv;

  double K[3][3];
#pragma unroll
  for (int i = 0; i < 3; ++i)
#pragma unroll
    for (int j = 0; j < 3; ++j)
      K[i][j] = H[0][i] * H[0][j] + H[1][i] * H[1][j] + H[2][i] * H[2][j];

  const double q = (K[0][0] + K[1][1] + K[2][2]) / 3.0;
  const double p1 = K[0][1] * K[0][1] + K[0][2] * K[0][2] + K[1][2] * K[1][2];
  const double a0 = K[0][0] - q, a1 = K[1][1] - q, a2 = K[2][2] - q;
  const double p2 = a0 * a0 + a1 * a1 + a2 * a2 + 2.0 * p1;
  double e1, e2, e3;
  if (p2 <= 1e-300) {
    e1 = e2 = e3 = q;
  } else {
    const double pp = sqrt(p2 / 6.0);
    const double ip = 1.0 / pp;
    const double B00 = a0 * ip, B11 = a1 * ip, B22 = a2 * ip;
    const double B01 = K[0][1] * ip, B02 = K[0][2] * ip, B12 = K[1][2] * ip;
    double r = 0.5 * (B00 * (B11 * B22 - B12 * B12) - B01 * (B01 * B22 - B12 * B02) +
                      B02 * (B01 * B12 - B11 * B02));
    float rf = fminf(1.0f, fmaxf(-1.0f, (float)r));
    const float phi = acosf(rf) * (1.0f / 3.0f);
    e1 = q + 2.0 * pp * (double)cosf(phi);
    e3 = q + 2.0 * pp * (double)cosf(phi + 2.0943951023931953f);
    e2 = 3.0 * q - e1 - e3;
  }
  const double s1 = sqrt(fmax(e1, 0.0));
  const double s2 = sqrt(fmax(e2, 0.0));
  const double s3 = sqrt(fmax(e3, 0.0));

  const double detH =
      H[0][0] * (H[1][1] * H[2][2] - H[1][2] * H[2][1]) -
      H[0][1] * (H[1][0] * H[2][2] - H[1][2] * H[2][0]) +
      H[0][2] * (H[1][0] * H[2][1] - H[1][1] * H[2][0]);
  const double d = (detH > 0.0) ? 1.0 : ((detH < 0.0) ? -1.0 : 0.0);

  const double cost = Sq + Sy - 2.0 * (s1 + s2 + d * s3);
  double tot = cost / (msum + 1e-6) * (double)scale[tid];
  tot *= 1.0 / (3.0 * (double)NS * (double)NB);

#pragma unroll
  for (int off = 32; off; off >>= 1) tot += __shfl_xor(tot, off, 64);
  __shared__ double red[FBS / 64];
  if ((tid & 63) == 0) red[tid >> 6] = tot;
  __syncthreads();
  if (tid == 0) {
    double s = 0.0;
#pragma unroll
    for (int w = 0; w < FBS / 64; ++w) s += red[w];
    out[0] = (float)s;
  }
}

}  // namespace

extern "C" void kernel_launch(void* const* d_in, const int* in_sizes, int n_in,
                              void* d_out, int out_size, void* d_ws, size_t ws_size,
                              hipStream_t stream) {
  const float* pred = (const float*)d_in[0];
  const float* truec = (const float*)d_in[1];
  const int* mask = (const int*)d_in[2];
  const int* dna = (const int*)d_in[3];
  const int* rna = (const int*)d_in[4];
  const int* lig = (const int*)d_in[5];
  const float* scale = (const float*)d_in[6];
  float* ws = (float*)d_ws;
  float* out = (float*)d_out;

  fused_kernel<<<GRID, BSIZE, 0, stream>>>(pred, truec, mask, dna, rna, lig, ws);
  final_kernel<<<1, FBS, 0, stream>>>(ws, scale, out);
}